// Round 1
// baseline (309.485 us; speedup 1.0000x reference)
//
#include <hip/hip_runtime.h>
#include <hip/hip_cooperative_groups.h>
#include <hip/hip_bf16.h>
#include <math.h>

namespace cg = cooperative_groups;

namespace {

constexpr int NB = 2, NS = 128, ND = 64, NF = 256;

typedef __attribute__((ext_vector_type(8))) short short8;
typedef __attribute__((ext_vector_type(8))) unsigned short ushort8;
typedef __attribute__((ext_vector_type(4))) float floatx4;

// workspace offsets (float units) — layout unchanged from baseline
constexpr size_t OFF_W2H  = 0;                                   // [B][S(j)][F][D] bf16
constexpr size_t SZ_W2H   = (size_t)NB * NS * NF * ND / 2;
constexpr size_t OFF_P    = OFF_W2H + SZ_W2H;                    // [B][S(j)][S(i)][D] bf16
constexpr size_t SZ_P     = (size_t)NB * NS * NS * ND / 2;
constexpr size_t OFF_AT   = OFF_P + SZ_P;                        // [B][F][S(i)] fp32
constexpr size_t SZ_AT    = (size_t)NB * NF * NS;
constexpr size_t OFF_BT   = OFF_AT + SZ_AT;                      // [B][S(j)][F] fp32 (+gb1)
constexpr size_t SZ_BT    = (size_t)NB * NS * NF;
constexpr size_t OFF_BIAS = OFF_BT + SZ_BT;                      // [B][D]

// A&S 7.1.26 erf: |err| <= 1.5e-7, branchless.
__device__ __forceinline__ float gelu_fast(float x) {
  const float xs = fabsf(x) * 0.70710678118654752f;
  const float t = __builtin_amdgcn_rcpf(fmaf(0.3275911f, xs, 1.0f));
  float p = fmaf(1.061405429f, t, -1.453152027f);
  p = fmaf(p, t, 1.421413741f);
  p = fmaf(p, t, -0.284496736f);
  p = fmaf(p, t, 0.254829592f);
  p *= t;
  const float e = __expf(-xs * xs);
  const float erf_ax = fmaf(-p, e, 1.0f);
  const float erf_x = copysignf(erf_ax, x);
  return 0.5f * x * (1.0f + erf_x);
}

__device__ __forceinline__ ushort8 pack_bf16x8(const float v[8]) {
  union { __hip_bfloat162 b2[4]; ushort8 u; } u;
  #pragma unroll
  for (int p = 0; p < 4; ++p)
    u.b2[p] = __float22bfloat162_rn(make_float2(v[2 * p], v[2 * p + 1]));
  return u.u;
}

__device__ __forceinline__ float bf16u_to_f(unsigned short u) {
  return __uint_as_float((unsigned)u << 16);
}

constexpr int HLD = 72;  // ushort stride for phase-B LDS tiles (2-way max conflicts)

// ---------------------------------------------------------------------------
// Single cooperative kernel: 256 wgs x 512 thr (1 wg/CU, 8 waves).
//  phase A (= old kA_pre):  bid<128 A_t/Bt | bid in [128,192) W2h | 192..193 bias
//  grid.sync()
//  phase B (= old k2_main): one wg per (b,j), MFMA P = gelu(A+B) @ W2h, bf16 out
//  grid.sync()
//  phase C (= old k3_epi):  one wg per (b,i): j-reduce, LN1, MLP, LN2
// ---------------------------------------------------------------------------
__global__ __launch_bounds__(512) void k_fused(
    const float* __restrict__ q,    const float* __restrict__ gw1,
    const float* __restrict__ gb1,  const float* __restrict__ gw2,
    const float* __restrict__ gb2,  const float* __restrict__ mw1,
    const float* __restrict__ mb1,  const float* __restrict__ mw2,
    const float* __restrict__ mb2,  const float* __restrict__ ln1g,
    const float* __restrict__ ln1b, const float* __restrict__ ln2g,
    const float* __restrict__ ln2b, float* __restrict__ out,
    float* __restrict__ A_t,        float* __restrict__ Bt,
    unsigned short* __restrict__ W2h, float* __restrict__ bias_agg,
    unsigned short* __restrict__ P) {
  // one shared arena, re-typed per phase (max user: phase A = 57344 B)
  __shared__ __align__(16) unsigned char smem_raw[57344];
  unsigned short* const smem_u = (unsigned short*)smem_raw;
  float* const smf = (float*)smem_raw;
  const int t = threadIdx.x;
  const int bid = blockIdx.x;

  // ============================ phase A ====================================
  if (bid < 128) {
    // ---- A_t / Bt (2 i's per block) ----
    const int b = bid >> 6, ip = bid & 63;
    const int half = t >> 8, f = t & 255;
    const int i = ip * 2 + half;
    float* qrow = smf;  // [2][64]
    if (f < ND) qrow[half * ND + f] = q[((size_t)b * NS + i) * ND + f];
    __syncthreads();
    float a = 0.f, bb = gb1[f];
    #pragma unroll 8
    for (int d = 0; d < ND; ++d) {
      const float qd = qrow[half * ND + d];
      a  += qd * gw1[d * NF + f];
      bb += qd * gw1[(ND + d) * NF + f];
    }
    A_t[((size_t)b * NF + f) * NS + i] = a;
    Bt[((size_t)b * NS + i) * NF + f] = bb;
  } else if (bid < 192) {
    // ---- W2h via MFMA: W2[b][j][f][e] = sum_d q[b][j][d] * gw2[f][d*64+e] ----
    const int idx = bid - 128;
    const int b = idx >> 5, f0 = (idx & 31) * 8;
    unsigned short* qbf = smem_u;             // [j][64] bf16, oct xor-swizzled
    unsigned short* Gt  = smem_u + 128 * 64;  // [f'][e][40] bf16
    {
      const int jq = t >> 1, half = t & 1;
      const float* src = q + ((size_t)b * NS + jq) * ND + half * 32;
      #pragma unroll
      for (int p = 0; p < 4; ++p) {
        float v[8];
        #pragma unroll
        for (int r = 0; r < 8; ++r) v[r] = src[p * 8 + r];
        const int oct = half * 4 + p;
        const int col = oct ^ (jq & 7);
        *(ushort8*)&qbf[jq * 64 + col * 8] = pack_bf16x8(v);
      }
    }
    const int lane = t & 63, w = t >> 6;
    const int f = f0 + w;
    const int m = lane & 15, quad = lane >> 4;
    const int te = t & 63, tf = t >> 6;
    floatx4 acc[8][4];
    #pragma unroll
    for (int ti = 0; ti < 8; ++ti)
      #pragma unroll
      for (int tn = 0; tn < 4; ++tn) acc[ti][tn] = (floatx4)0.f;

    for (int dc = 0; dc < 2; ++dc) {
      __syncthreads();
      const float* gsrc = gw2 + (size_t)(f0 + tf) * (ND * ND) + (size_t)(dc * 32) * ND + te;
      #pragma unroll
      for (int p = 0; p < 4; ++p) {
        float gv[8];
        #pragma unroll
        for (int r = 0; r < 8; ++r) gv[r] = gsrc[(size_t)(p * 8 + r) * ND];
        *(ushort8*)&Gt[tf * 2560 + te * 40 + p * 8] = pack_bf16x8(gv);
      }
      __syncthreads();
      short8 bfr[4];
      #pragma unroll
      for (int tn = 0; tn < 4; ++tn)
        bfr[tn] = *(const short8*)&Gt[w * 2560 + (tn * 16 + m) * 40 + quad * 8];
      #pragma unroll
      for (int ti = 0; ti < 8; ++ti) {
        const int jr = ti * 16 + m;
        const int col = (dc * 4 + quad) ^ (jr & 7);
        const short8 afr = *(const short8*)&qbf[jr * 64 + col * 8];
        #pragma unroll
        for (int tn = 0; tn < 4; ++tn)
          acc[ti][tn] = __builtin_amdgcn_mfma_f32_16x16x32_bf16(afr, bfr[tn],
                                                                acc[ti][tn], 0, 0, 0);
      }
    }
    __hip_bfloat16* Wh = (__hip_bfloat16*)W2h;
    #pragma unroll
    for (int ti = 0; ti < 8; ++ti)
      #pragma unroll
      for (int r = 0; r < 4; ++r) {
        const int jr = ti * 16 + quad * 4 + r;
        __hip_bfloat16* dst = Wh + ((size_t)(b * NS + jr) * NF + f) * ND;
        #pragma unroll
        for (int tn = 0; tn < 4; ++tn)
          dst[tn * 16 + m] = __float2bfloat16(acc[ti][tn][r]);
      }
  } else if (bid < 194) {
    // ---- bias_agg ----
    const int b = bid - 192;
    float* qs = smf;
    float* colsum = smf + NS * ND;
    for (int r = 0; r < 16; ++r) qs[t + r * 512] = q[(size_t)b * NS * ND + t + r * 512];
    __syncthreads();
    if (t < ND) {
      float s = 0.f;
      for (int jj = 0; jj < NS; ++jj) s += qs[jj * ND + t];
      colsum[t] = s;
    }
    __syncthreads();
    if (t < ND) {
      float a2 = 0.f;
      for (int d = 0; d < ND; ++d) a2 += gb2[d * ND + t] * colsum[d];
      bias_agg[b * ND + t] = a2;
    }
  }
  __threadfence();          // device-scope release of A_t/Bt/W2h/bias
  cg::this_grid().sync();

  // ============================ phase B ====================================
  {
    const int b = bid >> 7, j = bid & (NS - 1);
    const int lane = t & 63, w = t >> 6;
    float* const Btj = smf;                                              // NF f32
    unsigned short* const Hc = (unsigned short*)(smem_raw + 1024);       // NS*HLD
    unsigned short* const Wc = (unsigned short*)(smem_raw + 1024 + NS * HLD * 2);
    if (t < NF) Btj[t] = Bt[((size_t)b * NS + j) * NF + t];

    const unsigned short* Whbj = W2h + (size_t)(b * NS + j) * NF * ND;
    const float* Ab = A_t + (size_t)b * NF * NS;

    const int wi = (w & 3) * 32, we = (w >> 2) * 32;
    const int m = lane & 15, quad = lane >> 4;
    const int hi = (w & 1) * 64 + lane, hoct0 = w >> 1;
    const int wei = t & 63, woct = w;

    floatx4 acc[2][2];
    #pragma unroll
    for (int a0 = 0; a0 < 2; ++a0)
      #pragma unroll
      for (int a1 = 0; a1 < 2; ++a1) acc[a0][a1] = (floatx4)0.f;

    unsigned short wvv[8];
    #pragma unroll
    for (int r = 0; r < 8; ++r)
      wvv[r] = Whbj[(size_t)(woct * 8 + r) * ND + wei];
    float ar[2][8];
    #pragma unroll
    for (int s = 0; s < 2; ++s)
      #pragma unroll
      for (int r = 0; r < 8; ++r)
        ar[s][r] = Ab[(size_t)((hoct0 + 4 * s) * 8 + r) * NS + hi];
    __syncthreads();  // Btj visible (also orders LDS reuse after grid sync)

    for (int c = 0; c < NF / 64; ++c) {
      ushort8 hv[2];
      #pragma unroll
      for (int s = 0; s < 2; ++s) {
        float hvf[8];
        #pragma unroll
        for (int r = 0; r < 8; ++r) {
          const int fl = c * 64 + (hoct0 + 4 * s) * 8 + r;
          hvf[r] = gelu_fast(ar[s][r] + Btj[fl]);
        }
        hv[s] = pack_bf16x8(hvf);
      }
      union { unsigned short a[8]; ushort8 v; } wu;
      #pragma unroll
      for (int r = 0; r < 8; ++r) wu.a[r] = wvv[r];
      if (c > 0) __syncthreads();
      *(ushort8*)&Wc[wei * HLD + woct * 8] = wu.v;
      *(ushort8*)&Hc[hi * HLD + hoct0 * 8] = hv[0];
      *(ushort8*)&Hc[hi * HLD + (hoct0 + 4) * 8] = hv[1];
      if (c < NF / 64 - 1) {
        #pragma unroll
        for (int r = 0; r < 8; ++r)
          wvv[r] = Whbj[(size_t)((c + 1) * 64 + woct * 8 + r) * ND + wei];
        #pragma unroll
        for (int s = 0; s < 2; ++s)
          #pragma unroll
          for (int r = 0; r < 8; ++r)
            ar[s][r] = Ab[(size_t)((c + 1) * 64 + (hoct0 + 4 * s) * 8 + r) * NS + hi];
      }
      __syncthreads();
      #pragma unroll
      for (int kk = 0; kk < 2; ++kk) {
        short8 afr[2], bfr[2];
        #pragma unroll
        for (int ti = 0; ti < 2; ++ti)
          afr[ti] = *(const short8*)&Hc[(wi + ti * 16 + m) * HLD + kk * 32 + quad * 8];
        #pragma unroll
        for (int te = 0; te < 2; ++te)
          bfr[te] = *(const short8*)&Wc[(we + te * 16 + m) * HLD + kk * 32 + quad * 8];
        #pragma unroll
        for (int ti = 0; ti < 2; ++ti)
          #pragma unroll
          for (int te = 0; te < 2; ++te)
            acc[ti][te] = __builtin_amdgcn_mfma_f32_16x16x32_bf16(
                afr[ti], bfr[te], acc[ti][te], 0, 0, 0);
      }
    }
    // epilogue: D layout row=(lane>>4)*4+reg, col=lane&15; store bf16
    __hip_bfloat16* Pbj = (__hip_bfloat16*)(P + (size_t)(b * NS + j) * NS * ND);
    #pragma unroll
    for (int ti = 0; ti < 2; ++ti)
      #pragma unroll
      for (int te = 0; te < 2; ++te)
        #pragma unroll
        for (int r = 0; r < 4; ++r) {
          const int row = wi + ti * 16 + quad * 4 + r;
          const int col = we + te * 16 + m;
          Pbj[(size_t)row * ND + col] = __float2bfloat16(acc[ti][te][r]);
        }
  }
  __threadfence();          // device-scope release of P
  cg::this_grid().sync();

  // ============================ phase C ====================================
  {
    const int b = bid >> 7, i = bid & (NS - 1);
    const int e = t & 63, g = t >> 6;
    float* const red  = smf;             // [64][72] padded (72%32=8 -> conflict-light)
    float* const red2 = smf + 64 * 72;   // [8][64]
    float* const phi1 = red2 + 8 * 64;   // [64]
    float* const hid  = phi1 + ND;       // [256]
    const unsigned short* Pb = P + (size_t)b * NS * NS * ND;
    // vectorized j-reduce: ushort8 loads (1 KB per wave-instruction)
    {
      const int og = t >> 3, e0 = (t & 7) * 8;
      float s[8];
      #pragma unroll
      for (int k = 0; k < 8; ++k) s[k] = 0.f;
      #pragma unroll
      for (int hlf = 0; hlf < 2; ++hlf) {
        const int jj = og + hlf * 64;
        const ushort8 v = *(const ushort8*)&Pb[((size_t)jj * NS + i) * ND + e0];
        #pragma unroll
        for (int k = 0; k < 8; ++k) s[k] += bf16u_to_f(v[k]);
      }
      #pragma unroll
      for (int k = 0; k < 8; ++k) red[og * 72 + e0 + k] = s[k];
    }
    __syncthreads();
    {
      const int r = t >> 6;  // 8 row-groups of 8
      float p = 0.f;
      #pragma unroll
      for (int m0 = 0; m0 < 8; ++m0) p += red[(r * 8 + m0) * 72 + e];
      red2[r * 64 + e] = p;
    }
    __syncthreads();
    if (t < ND) {
      float agg = bias_agg[b * ND + e];
      #pragma unroll
      for (int gg = 0; gg < 8; ++gg) agg += red2[gg * 64 + e];
      const float x = q[((size_t)b * NS + i) * ND + e] + agg;
      float sum = x, sumsq = x * x;
      #pragma unroll
      for (int off = 32; off >= 1; off >>= 1) {
        sum += __shfl_xor(sum, off);
        sumsq += __shfl_xor(sumsq, off);
      }
      const float mu = sum * (1.f / 64.f);
      const float var = sumsq * (1.f / 64.f) - mu * mu;
      const float inv = rsqrtf(var + 1e-5f);
      phi1[e] = (x - mu) * inv * ln1g[e] + ln1b[e];
    }
    __syncthreads();
    if (t < NF) {
      float h = mb1[t];
      #pragma unroll 8
      for (int d = 0; d < ND; ++d) h += phi1[d] * mw1[d * NF + t];
      hid[t] = gelu_fast(h);
    }
    __syncthreads();
    {
      float p = 0.f;
      #pragma unroll 8
      for (int m0 = 0; m0 < 32; ++m0) {
        const int f = g * 32 + m0;
        p += hid[f] * mw2[f * ND + e];
      }
      red2[t] = p;
    }
    __syncthreads();
    if (t < ND) {
      float mlp = mb2[e];
      #pragma unroll
      for (int gg = 0; gg < 8; ++gg) mlp += red2[gg * 64 + e];
      const float x = phi1[e] + mlp;
      float sum = x, sumsq = x * x;
      #pragma unroll
      for (int off = 32; off >= 1; off >>= 1) {
        sum += __shfl_xor(sum, off);
        sumsq += __shfl_xor(sumsq, off);
      }
      const float mu = sum * (1.f / 64.f);
      const float var = sumsq * (1.f / 64.f) - mu * mu;
      const float inv = rsqrtf(var + 1e-5f);
      out[((size_t)b * NS + i) * ND + e] = (x - mu) * inv * ln2g[e] + ln2b[e];
    }
  }
}

}  // namespace

extern "C" void kernel_launch(void* const* d_in, const int* in_sizes, int n_in,
                              void* d_out, int out_size, void* d_ws, size_t ws_size,
                              hipStream_t stream) {
  const float* q    = (const float*)d_in[0];
  const float* gw1  = (const float*)d_in[1];
  const float* gb1  = (const float*)d_in[2];
  const float* gw2  = (const float*)d_in[3];
  const float* gb2  = (const float*)d_in[4];
  const float* mw1  = (const float*)d_in[5];
  const float* mb1  = (const float*)d_in[6];
  const float* mw2  = (const float*)d_in[7];
  const float* mb2  = (const float*)d_in[8];
  const float* ln1g = (const float*)d_in[9];
  const float* ln1b = (const float*)d_in[10];
  const float* ln2g = (const float*)d_in[11];
  const float* ln2b = (const float*)d_in[12];
  float* out = (float*)d_out;
  float* ws  = (float*)d_ws;

  unsigned short* W2h = (unsigned short*)(ws + OFF_W2H);
  unsigned short* Pp  = (unsigned short*)(ws + OFF_P);
  float* A_t  = ws + OFF_AT;
  float* Bt   = ws + OFF_BT;
  float* bias = ws + OFF_BIAS;

  void* args[] = {(void*)&q,    (void*)&gw1,  (void*)&gb1,  (void*)&gw2,
                  (void*)&gb2,  (void*)&mw1,  (void*)&mb1,  (void*)&mw2,
                  (void*)&mb2,  (void*)&ln1g, (void*)&ln1b, (void*)&ln2g,
                  (void*)&ln2b, (void*)&out,  (void*)&A_t,  (void*)&Bt,
                  (void*)&W2h,  (void*)&bias, (void*)&Pp};
  hipLaunchCooperativeKernel((const void*)k_fused, dim3(NB * NS), dim3(512),
                             args, 0, stream);
}

// Round 2
// 107.218 us; speedup vs baseline: 2.8865x; 2.8865x over previous
//
#include <hip/hip_runtime.h>
#include <hip/hip_bf16.h>
#include <math.h>

namespace {

constexpr int NB = 2, NS = 128, ND = 64, NF = 256;

typedef __attribute__((ext_vector_type(8))) short short8;
typedef __attribute__((ext_vector_type(8))) unsigned short ushort8;
typedef __attribute__((ext_vector_type(4))) float floatx4;

// workspace offsets (float units)
constexpr size_t OFF_W2H  = 0;                                   // [B][S(j)][F][D] bf16
constexpr size_t SZ_W2H   = (size_t)NB * NS * NF * ND / 2;       // ushorts in float space
constexpr size_t OFF_P    = OFF_W2H + SZ_W2H;                    // [B][S(j)][S(i)][D] bf16
constexpr size_t SZ_P     = (size_t)NB * NS * NS * ND / 2;       // ushorts in float space
constexpr size_t OFF_AT   = OFF_P + SZ_P;                        // [B][F][S(i)] fp32
constexpr size_t SZ_AT    = (size_t)NB * NF * NS;
constexpr size_t OFF_BT   = OFF_AT + SZ_AT;                      // [B][S(j)][F] fp32 (+gb1)
constexpr size_t SZ_BT    = (size_t)NB * NS * NF;
constexpr size_t OFF_BIAS = OFF_BT + SZ_BT;                      // [B][D]

// A&S 7.1.26 erf: |err| <= 1.5e-7, branchless.
__device__ __forceinline__ float gelu_fast(float x) {
  const float xs = fabsf(x) * 0.70710678118654752f;
  const float t = __builtin_amdgcn_rcpf(fmaf(0.3275911f, xs, 1.0f));
  float p = fmaf(1.061405429f, t, -1.453152027f);
  p = fmaf(p, t, 1.421413741f);
  p = fmaf(p, t, -0.284496736f);
  p = fmaf(p, t, 0.254829592f);
  p *= t;
  const float e = __expf(-xs * xs);
  const float erf_ax = fmaf(-p, e, 1.0f);
  const float erf_x = copysignf(erf_ax, x);
  return 0.5f * x * (1.0f + erf_x);
}

__device__ __forceinline__ ushort8 pack_bf16x8(const float v[8]) {
  union { __hip_bfloat162 b2[4]; ushort8 u; } u;
  #pragma unroll
  for (int p = 0; p < 4; ++p)
    u.b2[p] = __float22bfloat162_rn(make_float2(v[2 * p], v[2 * p + 1]));
  return u.u;
}

__device__ __forceinline__ float bf16u_to_f(unsigned short u) {
  return __uint_as_float((unsigned)u << 16);
}

// ---------------------------------------------------------------------------
// kA (512 thr): blocks [0,128)   : A_t / Bt  (2 i's per block)
//               blocks [128,192) : W2h[b][j][f][e] bf16 via MFMA (1 f/wave)
//               blocks [192,194) : bias_agg[b][e]
// ---------------------------------------------------------------------------
__global__ __launch_bounds__(512) void kA_pre(const float* __restrict__ q,
                                              const float* __restrict__ gw1,
                                              const float* __restrict__ gb1,
                                              const float* __restrict__ gw2,
                                              const float* __restrict__ gb2,
                                              float* __restrict__ A_t,
                                              float* __restrict__ Bt,
                                              unsigned short* __restrict__ W2h,
                                              float* __restrict__ bias_agg) {
  __shared__ __align__(16) unsigned short smem_u[128 * 64 + 8 * 64 * 40];  // 57344 B
  float* smf = (float*)smem_u;
  const int t = threadIdx.x, bid = blockIdx.x;

  if (bid < 128) {
    // ---- A_t / Bt ----
    const int b = bid >> 6, ip = bid & 63;
    const int half = t >> 8, f = t & 255;
    const int i = ip * 2 + half;
    float* qrow = smf;  // [2][64]
    if (f < 64) qrow[half * 64 + f] = q[((size_t)b * NS + i) * ND + f];
    __syncthreads();
    float a = 0.f, bb = gb1[f];
    #pragma unroll 8
    for (int d = 0; d < ND; ++d) {
      const float qd = qrow[half * 64 + d];
      a  += qd * gw1[d * NF + f];
      bb += qd * gw1[(ND + d) * NF + f];
    }
    A_t[((size_t)b * NF + f) * NS + i] = a;
    Bt[((size_t)b * NS + i) * NF + f] = bb;
  } else if (bid < 192) {
    // ---- W2h via MFMA: W2[b][j][f][e] = sum_d q[b][j][d] * gw2[f][d*64+e] ----
    const int idx = bid - 128;
    const int b = idx >> 5, f0 = (idx & 31) * 8;
    unsigned short* qbf = smem_u;             // [j][64] bf16, oct xor-swizzled by (j&7)
    unsigned short* Gt  = smem_u + 128 * 64;  // [f'][e][40] bf16 (d-contig, pad 40)
    {
      const int jq = t >> 1, half = t & 1;
      const float* src = q + ((size_t)b * NS + jq) * ND + half * 32;
      #pragma unroll
      for (int p = 0; p < 4; ++p) {
        float v[8];
        #pragma unroll
        for (int r = 0; r < 8; ++r) v[r] = src[p * 8 + r];
        const int oct = half * 4 + p;
        const int col = oct ^ (jq & 7);
        *(ushort8*)&qbf[jq * 64 + col * 8] = pack_bf16x8(v);
      }
    }
    const int lane = t & 63, w = t >> 6;
    const int f = f0 + w;
    const int m = lane & 15, quad = lane >> 4;
    const int te = t & 63, tf = t >> 6;
    floatx4 acc[8][4];
    #pragma unroll
    for (int ti = 0; ti < 8; ++ti)
      #pragma unroll
      for (int tn = 0; tn < 4; ++tn) acc[ti][tn] = (floatx4)0.f;

    for (int dc = 0; dc < 2; ++dc) {
      __syncthreads();
      const float* gsrc = gw2 + (size_t)(f0 + tf) * (ND * ND) + (size_t)(dc * 32) * ND + te;
      #pragma unroll
      for (int p = 0; p < 4; ++p) {
        float gv[8];
        #pragma unroll
        for (int r = 0; r < 8; ++r) gv[r] = gsrc[(size_t)(p * 8 + r) * ND];
        *(ushort8*)&Gt[tf * 2560 + te * 40 + p * 8] = pack_bf16x8(gv);
      }
      __syncthreads();
      short8 bfr[4];
      #pragma unroll
      for (int tn = 0; tn < 4; ++tn)
        bfr[tn] = *(const short8*)&Gt[w * 2560 + (tn * 16 + m) * 40 + quad * 8];
      #pragma unroll
      for (int ti = 0; ti < 8; ++ti) {
        const int jr = ti * 16 + m;
        const int col = (dc * 4 + quad) ^ (jr & 7);
        const short8 afr = *(const short8*)&qbf[jr * 64 + col * 8];
        #pragma unroll
        for (int tn = 0; tn < 4; ++tn)
          acc[ti][tn] = __builtin_amdgcn_mfma_f32_16x16x32_bf16(afr, bfr[tn],
                                                                acc[ti][tn], 0, 0, 0);
      }
    }
    __hip_bfloat16* Wh = (__hip_bfloat16*)W2h;
    #pragma unroll
    for (int ti = 0; ti < 8; ++ti)
      #pragma unroll
      for (int r = 0; r < 4; ++r) {
        const int jr = ti * 16 + quad * 4 + r;
        __hip_bfloat16* dst = Wh + ((size_t)(b * NS + jr) * NF + f) * ND;
        #pragma unroll
        for (int tn = 0; tn < 4; ++tn)
          dst[tn * 16 + m] = __float2bfloat16(acc[ti][tn][r]);
      }
  } else {
    // ---- bias_agg ----
    const int b = bid - 192;
    float* qs = smf;
    float* colsum = smf + NS * ND;
    for (int r = 0; r < 16; ++r) qs[t + r * 512] = q[(size_t)b * NS * ND + t + r * 512];
    __syncthreads();
    if (t < ND) {
      float s = 0.f;
      for (int jj = 0; jj < NS; ++jj) s += qs[jj * ND + t];
      colsum[t] = s;
    }
    __syncthreads();
    if (t < ND) {
      float a2 = 0.f;
      for (int d = 0; d < ND; ++d) a2 += gb2[d * ND + t] * colsum[d];
      bias_agg[b * ND + t] = a2;
    }
  }
}

// ---------------------------------------------------------------------------
// k2: one wg (512 thr, 8 waves) per (b,j). MFMA bf16 16x16x32, fp32 accum.
//   P[i][e] = sum_f gelu(A_t[f][i]+Btj[f]) * W2h[f][e],  M=128,N=64,K=256
// Output P stored bf16 (halves P HBM traffic; error << threshold).
// ---------------------------------------------------------------------------
constexpr int HLD = 72;  // ushort stride: 144 B -> frag reads 2-way max

__global__ __launch_bounds__(512) void k2_main(const float* __restrict__ A_t,
                                               const float* __restrict__ Bt,
                                               const unsigned short* __restrict__ W2h,
                                               unsigned short* __restrict__ P) {
  const int b = blockIdx.x / NS, j = blockIdx.x % NS;
  const int t = threadIdx.x;
  const int lane = t & 63, w = t >> 6;
  __shared__ float Btj[NF];
  __shared__ __align__(16) unsigned short Hc[NS * HLD];
  __shared__ __align__(16) unsigned short Wc[ND * HLD];
  if (t < NF) Btj[t] = Bt[((size_t)b * NS + j) * NF + t];

  const unsigned short* Whbj = W2h + (size_t)(b * NS + j) * NF * ND;
  const float* Ab = A_t + (size_t)b * NF * NS;

  const int wi = (w & 3) * 32, we = (w >> 2) * 32;
  const int m = lane & 15, quad = lane >> 4;
  const int hi = (w & 1) * 64 + lane, hoct0 = w >> 1;
  const int wei = t & 63, woct = w;

  floatx4 acc[2][2];
  #pragma unroll
  for (int a0 = 0; a0 < 2; ++a0)
    #pragma unroll
    for (int a1 = 0; a1 < 2; ++a1) acc[a0][a1] = (floatx4)0.f;

  unsigned short wvv[8];
  #pragma unroll
  for (int r = 0; r < 8; ++r)
    wvv[r] = Whbj[(size_t)(woct * 8 + r) * ND + wei];
  float ar[2][8];
  #pragma unroll
  for (int s = 0; s < 2; ++s)
    #pragma unroll
    for (int r = 0; r < 8; ++r)
      ar[s][r] = Ab[(size_t)((hoct0 + 4 * s) * 8 + r) * NS + hi];
  __syncthreads();  // Btj visible

  for (int c = 0; c < NF / 64; ++c) {
    ushort8 hv[2];
    #pragma unroll
    for (int s = 0; s < 2; ++s) {
      float hvf[8];
      #pragma unroll
      for (int r = 0; r < 8; ++r) {
        const int fl = c * 64 + (hoct0 + 4 * s) * 8 + r;
        hvf[r] = gelu_fast(ar[s][r] + Btj[fl]);
      }
      hv[s] = pack_bf16x8(hvf);
    }
    union { unsigned short a[8]; ushort8 v; } wu;
    #pragma unroll
    for (int r = 0; r < 8; ++r) wu.a[r] = wvv[r];
    if (c > 0) __syncthreads();
    *(ushort8*)&Wc[wei * HLD + woct * 8] = wu.v;
    *(ushort8*)&Hc[hi * HLD + hoct0 * 8] = hv[0];
    *(ushort8*)&Hc[hi * HLD + (hoct0 + 4) * 8] = hv[1];
    if (c < NF / 64 - 1) {
      #pragma unroll
      for (int r = 0; r < 8; ++r)
        wvv[r] = Whbj[(size_t)((c + 1) * 64 + woct * 8 + r) * ND + wei];
      #pragma unroll
      for (int s = 0; s < 2; ++s)
        #pragma unroll
        for (int r = 0; r < 8; ++r)
          ar[s][r] = Ab[(size_t)((c + 1) * 64 + (hoct0 + 4 * s) * 8 + r) * NS + hi];
    }
    __syncthreads();
    #pragma unroll
    for (int kk = 0; kk < 2; ++kk) {
      short8 afr[2], bfr[2];
      #pragma unroll
      for (int ti = 0; ti < 2; ++ti)
        afr[ti] = *(const short8*)&Hc[(wi + ti * 16 + m) * HLD + kk * 32 + quad * 8];
      #pragma unroll
      for (int te = 0; te < 2; ++te)
        bfr[te] = *(const short8*)&Wc[(we + te * 16 + m) * HLD + kk * 32 + quad * 8];
      #pragma unroll
      for (int ti = 0; ti < 2; ++ti)
        #pragma unroll
        for (int te = 0; te < 2; ++te)
          acc[ti][te] = __builtin_amdgcn_mfma_f32_16x16x32_bf16(
              afr[ti], bfr[te], acc[ti][te], 0, 0, 0);
    }
  }
  // epilogue: D layout row=(lane>>4)*4+reg, col=lane&15; store bf16
  __hip_bfloat16* Pbj = (__hip_bfloat16*)(P + (size_t)(b * NS + j) * NS * ND);
  #pragma unroll
  for (int ti = 0; ti < 2; ++ti)
    #pragma unroll
    for (int te = 0; te < 2; ++te)
      #pragma unroll
      for (int r = 0; r < 4; ++r) {
        const int row = wi + ti * 16 + quad * 4 + r;
        const int col = we + te * 16 + m;
        Pbj[(size_t)row * ND + col] = __float2bfloat16(acc[ti][te][r]);
      }
}

// ---------------------------------------------------------------------------
// k3: one wg (512 thr) per (b,i): agg-reduce over j (bf16 P, ushort8 loads),
// LN1, MLP, LN2.  P reduce: each thread sums 2 j's for 8 contiguous e's, then
// padded-stride LDS transpose + two-stage reduce.
// ---------------------------------------------------------------------------
__global__ __launch_bounds__(512) void k3_epi(const float* __restrict__ q,
                                              const unsigned short* __restrict__ P,
                                              const float* __restrict__ bias_agg,
                                              const float* __restrict__ mw1,
                                              const float* __restrict__ mb1,
                                              const float* __restrict__ mw2,
                                              const float* __restrict__ mb2,
                                              const float* __restrict__ ln1g,
                                              const float* __restrict__ ln1b,
                                              const float* __restrict__ ln2g,
                                              const float* __restrict__ ln2b,
                                              float* __restrict__ out) {
  const int b = blockIdx.x / NS, i = blockIdx.x % NS;
  const int t = threadIdx.x;
  const int e = t & 63, g = t >> 6;
  __shared__ float red[64 * 72];   // [og][72] padded (72%32=8 -> conflict-light)
  __shared__ float red2[8 * 64];
  __shared__ float phi1[ND];
  __shared__ float hid[NF];
  const unsigned short* Pb = P + (size_t)b * NS * NS * ND;
  // vectorized j-reduce: ushort8 loads (16 B/lane)
  {
    const int og = t >> 3, e0 = (t & 7) * 8;
    float s[8];
    #pragma unroll
    for (int k = 0; k < 8; ++k) s[k] = 0.f;
    #pragma unroll
    for (int hlf = 0; hlf < 2; ++hlf) {
      const int jj = og + hlf * 64;
      const ushort8 v = *(const ushort8*)&Pb[((size_t)jj * NS + i) * ND + e0];
      #pragma unroll
      for (int k = 0; k < 8; ++k) s[k] += bf16u_to_f(v[k]);
    }
    #pragma unroll
    for (int k = 0; k < 8; ++k) red[og * 72 + e0 + k] = s[k];
  }
  __syncthreads();
  {
    const int r = t >> 6;  // 8 row-groups of 8 og's each
    float p = 0.f;
    #pragma unroll
    for (int m0 = 0; m0 < 8; ++m0) p += red[(r * 8 + m0) * 72 + e];
    red2[r * 64 + e] = p;
  }
  __syncthreads();
  if (t < ND) {
    float agg = bias_agg[b * ND + e];
    #pragma unroll
    for (int gg = 0; gg < 8; ++gg) agg += red2[gg * 64 + e];
    const float x = q[((size_t)b * NS + i) * ND + e] + agg;
    float sum = x, sumsq = x * x;
    #pragma unroll
    for (int off = 32; off >= 1; off >>= 1) {
      sum += __shfl_xor(sum, off);
      sumsq += __shfl_xor(sumsq, off);
    }
    const float mu = sum * (1.f / 64.f);
    const float var = sumsq * (1.f / 64.f) - mu * mu;
    const float inv = rsqrtf(var + 1e-5f);
    phi1[e] = (x - mu) * inv * ln1g[e] + ln1b[e];
  }
  __syncthreads();
  if (t < NF) {
    float h = mb1[t];
    #pragma unroll 8
    for (int d = 0; d < ND; ++d) h += phi1[d] * mw1[d * NF + t];
    hid[t] = gelu_fast(h);
  }
  __syncthreads();
  {
    float p = 0.f;
    #pragma unroll 8
    for (int m0 = 0; m0 < 32; ++m0) {
      const int f = g * 32 + m0;
      p += hid[f] * mw2[f * ND + e];
    }
    red2[t] = p;
  }
  __syncthreads();
  if (t < ND) {
    float mlp = mb2[e];
    #pragma unroll
    for (int gg = 0; gg < 8; ++gg) mlp += red2[gg * 64 + e];
    const float x = phi1[e] + mlp;
    float sum = x, sumsq = x * x;
    #pragma unroll
    for (int off = 32; off >= 1; off >>= 1) {
      sum += __shfl_xor(sum, off);
      sumsq += __shfl_xor(sumsq, off);
    }
    const float mu = sum * (1.f / 64.f);
    const float var = sumsq * (1.f / 64.f) - mu * mu;
    const float inv = rsqrtf(var + 1e-5f);
    out[((size_t)b * NS + i) * ND + e] = (x - mu) * inv * ln2g[e] + ln2b[e];
  }
}

}  // namespace

extern "C" void kernel_launch(void* const* d_in, const int* in_sizes, int n_in,
                              void* d_out, int out_size, void* d_ws, size_t ws_size,
                              hipStream_t stream) {
  const float* q    = (const float*)d_in[0];
  const float* gw1  = (const float*)d_in[1];
  const float* gb1  = (const float*)d_in[2];
  const float* gw2  = (const float*)d_in[3];
  const float* gb2  = (const float*)d_in[4];
  const float* mw1  = (const float*)d_in[5];
  const float* mb1  = (const float*)d_in[6];
  const float* mw2  = (const float*)d_in[7];
  const float* mb2  = (const float*)d_in[8];
  const float* ln1g = (const float*)d_in[9];
  const float* ln1b = (const float*)d_in[10];
  const float* ln2g = (const float*)d_in[11];
  const float* ln2b = (const float*)d_in[12];
  float* out = (float*)d_out;
  float* ws  = (float*)d_ws;

  unsigned short* W2h = (unsigned short*)(ws + OFF_W2H);
  unsigned short* Pp  = (unsigned short*)(ws + OFF_P);
  float* A_t  = ws + OFF_AT;
  float* Bt   = ws + OFF_BT;
  float* bias = ws + OFF_BIAS;

  kA_pre<<<194, 512, 0, stream>>>(q, gw1, gb1, gw2, gb2, A_t, Bt, W2h, bias);
  k2_main<<<NB * NS, 512, 0, stream>>>(A_t, Bt, W2h, Pp);
  k3_epi<<<NB * NS, 512, 0, stream>>>(q, Pp, bias, mw1, mb1, mw2, mb2,
                                      ln1g, ln1b, ln2g, ln2b, out);
}